// Round 5
// baseline (596.468 us; speedup 1.0000x reference)
//
#include <hip/hip_runtime.h>

#define TT 512
#define II 10
#define HH 32
#define LOG2E 1.44269504088896340736f

typedef float v2f __attribute__((ext_vector_type(2)));

// raw cross-half exchange: partner lane = lane ^ 32; bp precomputed once.
__device__ __forceinline__ float xchg32(int bp, float v) {
    return __builtin_bit_cast(float, __builtin_amdgcn_ds_bpermute(bp, __builtin_bit_cast(int, v)));
}

// Layout: wave = 1 batch row; lane = (unit j = lane&31, k-half kh = lane>>5).
// k-split is register-OPTIMAL: 5376 MACs/row-step / 64 lanes = 84 weight
// floats/lane (4 gates x (16 W_hh + ~5 W_ih)). waves_per_eu(4) pins the
// TOTAL unified budget to 128/wave so the allocator cannot park weights in
// AGPRs (R3/R4 lost 100-240 cyc/step to v_accvgpr_read per-use copies).
// All weights pre-scaled by log2e (gate g by 2*log2e): every activation is
// the same rcp(1+exp2(-s)) kernel; tanh fixup = one fma.
// Each wave owns its row's LDS h slots -> zero __syncthreads; DS ops are
// in-order within a wave (write t visible to reads t+1).
extern "C" __global__ __launch_bounds__(256)
__attribute__((amdgpu_waves_per_eu(4)))
void lstm_fused(const float* __restrict__ x,
                const float* __restrict__ h0,
                const float* __restrict__ c0,
                const float* __restrict__ W_ih,
                const float* __restrict__ W_hh,
                const float* __restrict__ b_ih,
                const float* __restrict__ b_hh,
                const float* __restrict__ W_lin,
                const float* __restrict__ b_lin,
                float* __restrict__ out)
{
    __shared__ __align__(16) float h_lds[4][HH];

    const int tid  = threadIdx.x;
    const int wv   = tid >> 6;
    const int lane = tid & 63;
    const int kh   = lane >> 5;
    const int j    = lane & 31;
    const bool khb = (kh != 0);
    const int b    = blockIdx.x * 4 + wv;
    const int bp   = (lane ^ 32) << 2;   // ds_bpermute byte address

    // ---- weights into registers, k-paired, PRE-SCALED by log2e ----
    v2f w[4][8];    // W_hh[g-row][kh*16 + 2q .. +2q+1] * scale
    v2f wi[4][3];   // x pairs; kh1's third = {bias*scale, 0} (virtual input {1,.})
    #pragma unroll
    for (int g = 0; g < 4; ++g) {
        const float sc = (g == 2) ? 2.0f * LOG2E : LOG2E;  // g-gate: tanh = 2*sig(2a)-1
        const int row = g * HH + j;
        const float4* wr = reinterpret_cast<const float4*>(W_hh + row * HH + kh * 16);
        #pragma unroll
        for (int q = 0; q < 4; ++q) {
            const float4 v = wr[q];
            w[g][2 * q + 0] = v2f{v.x * sc, v.y * sc};
            w[g][2 * q + 1] = v2f{v.z * sc, v.w * sc};
        }
        const float* qi = W_ih + row * II;
        if (!khb) {
            wi[g][0] = v2f{qi[0] * sc, qi[1] * sc};
            wi[g][1] = v2f{qi[2] * sc, qi[3] * sc};
            wi[g][2] = v2f{qi[4] * sc, qi[5] * sc};
        } else {
            wi[g][0] = v2f{qi[6] * sc, qi[7] * sc};
            wi[g][1] = v2f{qi[8] * sc, qi[9] * sc};
            wi[g][2] = v2f{(b_ih[row] + b_hh[row]) * sc, 0.0f};
        }
    }

    float c = c0[b * HH + j];        // identical on both halves
    h_lds[wv][j] = h0[b * HH + j];   // lanes j, j+32: same addr, same value
    float hv = 0.0f;

    // x addressing: sgpr base + 32-bit voffset (max ~84MB, fits u32).
    // kh0 pairs at +0,+2,+4; kh1 pairs at +6,+8, third reloads +8 (always
    // in-bounds; its .x is replaced by 1.0 for the bias virtual input).
    unsigned xoff  = (unsigned)b * (TT * II) + (khb ? 6u : 0u);
    unsigned xoff2 = xoff + (khb ? 2u : 4u);

    const v2f* hrow = reinterpret_cast<const v2f*>(&h_lds[wv][kh * 16]);

    #pragma unroll 2
    for (int t = 0; t < TT; ++t) {
        // current-step x (issue early; x-FMAs placed after the h-FMA block)
        const v2f p0  = *reinterpret_cast<const v2f*>(x + xoff);
        const v2f p1  = *reinterpret_cast<const v2f*>(x + xoff + 2);
        const v2f ld2 = *reinterpret_cast<const v2f*>(x + xoff2);
        xoff += II; xoff2 += II;

        // recurrent partials over this k-half: 32 pk_fma
        v2f a0 = w[0][0] * hrow[0];
        v2f a1 = w[1][0] * hrow[0];
        v2f a2 = w[2][0] * hrow[0];
        v2f a3 = w[3][0] * hrow[0];
        #pragma unroll
        for (int q = 1; q < 8; ++q) {
            const v2f hq = hrow[q];
            a0 = __builtin_elementwise_fma(w[0][q], hq, a0);
            a1 = __builtin_elementwise_fma(w[1][q], hq, a1);
            a2 = __builtin_elementwise_fma(w[2][q], hq, a2);
            a3 = __builtin_elementwise_fma(w[3][q], hq, a3);
        }

        // x partials: 12 pk_fma (+1 cndmask for the bias virtual input)
        const v2f p2 = v2f{khb ? 1.0f : ld2.x, ld2.y};
        a0 = __builtin_elementwise_fma(wi[0][0], p0, a0);
        a1 = __builtin_elementwise_fma(wi[1][0], p0, a1);
        a2 = __builtin_elementwise_fma(wi[2][0], p0, a2);
        a3 = __builtin_elementwise_fma(wi[3][0], p0, a3);
        a0 = __builtin_elementwise_fma(wi[0][1], p1, a0);
        a1 = __builtin_elementwise_fma(wi[1][1], p1, a1);
        a2 = __builtin_elementwise_fma(wi[2][1], p1, a2);
        a3 = __builtin_elementwise_fma(wi[3][1], p1, a3);
        a0 = __builtin_elementwise_fma(wi[0][2], p2, a0);
        a1 = __builtin_elementwise_fma(wi[1][2], p2, a1);
        a2 = __builtin_elementwise_fma(wi[2][2], p2, a2);
        a3 = __builtin_elementwise_fma(wi[3][2], p2, a3);

        // horizontal + cross-half combine (1 ds_bpermute each, addr precomputed)
        float s0 = a0.x + a0.y;
        float s1 = a1.x + a1.y;
        float s2 = a2.x + a2.y;
        float s3 = a3.x + a3.y;
        s0 += xchg32(bp, s0);
        s1 += xchg32(bp, s1);
        s2 += xchg32(bp, s2);
        s3 += xchg32(bp, s3);

        // activations: all four share the rcp(1+exp2(-s)) kernel (pre-scaled)
        const float r0 = __builtin_amdgcn_rcpf(1.0f + exp2f(-s0));  // i
        const float r1 = __builtin_amdgcn_rcpf(1.0f + exp2f(-s1));  // f
        const float r2 = __builtin_amdgcn_rcpf(1.0f + exp2f(-s2));  // sig(2g')
        const float r3 = __builtin_amdgcn_rcpf(1.0f + exp2f(-s3));  // o
        const float gg = 2.0f * r2 - 1.0f;                          // tanh(g')
        c = r1 * c + r0 * gg;
        const float rt = __builtin_amdgcn_rcpf(1.0f + exp2f(-2.0f * LOG2E * c));
        hv = r3 * (2.0f * rt - 1.0f);
        h_lds[wv][j] = hv;           // both halves, same addr/value; in-wave order
    }

    // out[b] = dot(hT, W_lin) + b_lin -- butterfly within each 32-lane half
    float p = hv * W_lin[j];
    p += __shfl_xor(p, 1);
    p += __shfl_xor(p, 2);
    p += __shfl_xor(p, 4);
    p += __shfl_xor(p, 8);
    p += __shfl_xor(p, 16);
    if (lane == 0) out[b] = p + b_lin[0];
}

extern "C" void kernel_launch(void* const* d_in, const int* in_sizes, int n_in,
                              void* d_out, int out_size, void* d_ws, size_t ws_size,
                              hipStream_t stream) {
    const float* x     = (const float*)d_in[0];
    const float* h0    = (const float*)d_in[1];
    const float* c0    = (const float*)d_in[2];
    const float* W_ih  = (const float*)d_in[3];
    const float* W_hh  = (const float*)d_in[4];
    const float* b_ih  = (const float*)d_in[5];
    const float* b_hh  = (const float*)d_in[6];
    const float* W_lin = (const float*)d_in[7];
    const float* b_lin = (const float*)d_in[8];
    float* out = (float*)d_out;

    const int B = in_sizes[1] / HH;   // 4096
    dim3 grid(B / 4), block(256);
    lstm_fused<<<grid, block, 0, stream>>>(x, h0, c0, W_ih, W_hh, b_ih, b_hh, W_lin, b_lin, out);
}

// Round 6
// 573.651 us; speedup vs baseline: 1.0398x; 1.0398x over previous
//
#include <hip/hip_runtime.h>

#define TT 512
#define II 10
#define HH 32
#define LOG2E 1.44269504088896340736f

typedef float v2f __attribute__((ext_vector_type(2)));

// raw cross-half exchange: partner lane = lane ^ 32; bp precomputed once.
__device__ __forceinline__ float xchg32(int bp, float v) {
    return __builtin_bit_cast(float, __builtin_amdgcn_ds_bpermute(bp, __builtin_bit_cast(int, v)));
}

// Layout: wave = 1 batch row; lane = (unit j = lane&31, k-half kh = lane>>5).
// k-split is register-OPTIMAL: 84 weight floats/lane. Allocator findings
// (R1-R5): waves_per_eu(2,2) grants 128+ ARCH VGPRs from a 256 unified
// budget; waves_per_eu(4) or amdgpu_num_vgpr(128) cap the TOTAL at 128 and
// the allocator splits it (64/88 arch + rest AGPR) -> v_accvgpr_read tax on
// every parked weight use. Here: demand ~125 < grant -> weights genuinely
// live in arch VGPRs, no tax. 2 waves/SIMD resident hide LDS/L2 latency.
// Weights pre-scaled by log2e (g-gate by 2*log2e): all activations share the
// rcp(1+exp2(-s)) kernel. Wave owns its row's LDS h slots -> no barriers.
extern "C" __global__ __launch_bounds__(256)
__attribute__((amdgpu_waves_per_eu(2, 2)))
void lstm_fused(const float* __restrict__ x,
                const float* __restrict__ h0,
                const float* __restrict__ c0,
                const float* __restrict__ W_ih,
                const float* __restrict__ W_hh,
                const float* __restrict__ b_ih,
                const float* __restrict__ b_hh,
                const float* __restrict__ W_lin,
                const float* __restrict__ b_lin,
                float* __restrict__ out)
{
    __shared__ __align__(16) float h_lds[4][HH];

    const int tid  = threadIdx.x;
    const int wv   = tid >> 6;
    const int lane = tid & 63;
    const int kh   = lane >> 5;
    const int j    = lane & 31;
    const bool khb = (kh != 0);
    const int b    = blockIdx.x * 4 + wv;
    const int bp   = (lane ^ 32) << 2;   // ds_bpermute byte address

    // ---- weights into registers, k-paired, PRE-SCALED by log2e ----
    v2f w[4][8];    // W_hh[g-row][kh*16 + 2q .. +2q+1] * scale
    v2f wi[4][3];   // x pairs; kh1's third = {bias*scale, 0} (virtual input {1,.})
    #pragma unroll
    for (int g = 0; g < 4; ++g) {
        const float sc = (g == 2) ? 2.0f * LOG2E : LOG2E;  // g-gate: tanh = 2*sig(2a)-1
        const int row = g * HH + j;
        const float4* wr = reinterpret_cast<const float4*>(W_hh + row * HH + kh * 16);
        #pragma unroll
        for (int q = 0; q < 4; ++q) {
            const float4 v = wr[q];
            w[g][2 * q + 0] = v2f{v.x * sc, v.y * sc};
            w[g][2 * q + 1] = v2f{v.z * sc, v.w * sc};
        }
        const float* qi = W_ih + row * II;
        if (!khb) {
            wi[g][0] = v2f{qi[0] * sc, qi[1] * sc};
            wi[g][1] = v2f{qi[2] * sc, qi[3] * sc};
            wi[g][2] = v2f{qi[4] * sc, qi[5] * sc};
        } else {
            wi[g][0] = v2f{qi[6] * sc, qi[7] * sc};
            wi[g][1] = v2f{qi[8] * sc, qi[9] * sc};
            wi[g][2] = v2f{(b_ih[row] + b_hh[row]) * sc, 0.0f};
        }
    }

    float c = c0[b * HH + j];        // identical on both halves
    h_lds[wv][j] = h0[b * HH + j];   // lanes j, j+32: same addr, same value
    float hv = 0.0f;

    // x addressing: running 32-bit offset, +II per consumed step (in step
    // order, so one running pointer serves the ping-pong prefetch).
    // kh0 pairs at +0,+2,+4; kh1 pairs at +6,+8 and third reloads +8
    // (its .x replaced by 1.0 -> bias virtual input). No clamps: last
    // prefetch is step TT-1, always in-bounds.
    unsigned xoff = (unsigned)b * (TT * II) + (khb ? 6u : 0u);
    const unsigned k2off = khb ? 2u : 4u;

    const v2f* hrow = reinterpret_cast<const v2f*>(&h_lds[wv][kh * 16]);

    v2f pa0, pa1, la2, pb0, pb1, lb2;

    #define PREFETCH(P0, P1, L2X)                                             \
        {                                                                     \
            P0  = *reinterpret_cast<const v2f*>(x + xoff);                    \
            P1  = *reinterpret_cast<const v2f*>(x + xoff + 2);                \
            L2X = *reinterpret_cast<const v2f*>(x + xoff + k2off);            \
            xoff += II;                                                       \
        }

    #define STEP(P0, P1, L2X)                                                 \
        {                                                                     \
            /* recurrent partials over this k-half: 32 pk_fma */              \
            v2f a0 = w[0][0] * hrow[0];                                       \
            v2f a1 = w[1][0] * hrow[0];                                       \
            v2f a2 = w[2][0] * hrow[0];                                       \
            v2f a3 = w[3][0] * hrow[0];                                       \
            _Pragma("unroll")                                                 \
            for (int q = 1; q < 8; ++q) {                                     \
                const v2f hq = hrow[q];                                       \
                a0 = __builtin_elementwise_fma(w[0][q], hq, a0);              \
                a1 = __builtin_elementwise_fma(w[1][q], hq, a1);              \
                a2 = __builtin_elementwise_fma(w[2][q], hq, a2);              \
                a3 = __builtin_elementwise_fma(w[3][q], hq, a3);              \
            }                                                                 \
            /* x partials: 12 pk_fma + 1 cndmask (bias virtual input) */      \
            const v2f p2 = v2f{khb ? 1.0f : (L2X).x, (L2X).y};                \
            a0 = __builtin_elementwise_fma(wi[0][0], (P0), a0);               \
            a1 = __builtin_elementwise_fma(wi[1][0], (P0), a1);               \
            a2 = __builtin_elementwise_fma(wi[2][0], (P0), a2);               \
            a3 = __builtin_elementwise_fma(wi[3][0], (P0), a3);               \
            a0 = __builtin_elementwise_fma(wi[0][1], (P1), a0);               \
            a1 = __builtin_elementwise_fma(wi[1][1], (P1), a1);               \
            a2 = __builtin_elementwise_fma(wi[2][1], (P1), a2);               \
            a3 = __builtin_elementwise_fma(wi[3][1], (P1), a3);               \
            a0 = __builtin_elementwise_fma(wi[0][2], p2, a0);                 \
            a1 = __builtin_elementwise_fma(wi[1][2], p2, a1);                 \
            a2 = __builtin_elementwise_fma(wi[2][2], p2, a2);                 \
            a3 = __builtin_elementwise_fma(wi[3][2], p2, a3);                 \
            /* horizontal + cross-half combine */                             \
            float s0 = a0.x + a0.y;                                           \
            float s1 = a1.x + a1.y;                                           \
            float s2 = a2.x + a2.y;                                           \
            float s3 = a3.x + a3.y;                                           \
            s0 += xchg32(bp, s0);                                             \
            s1 += xchg32(bp, s1);                                             \
            s2 += xchg32(bp, s2);                                             \
            s3 += xchg32(bp, s3);                                             \
            /* activations: shared rcp(1+exp2(-s)) kernel (pre-scaled) */     \
            const float r0 = __builtin_amdgcn_rcpf(1.0f + exp2f(-s0));        \
            const float r1 = __builtin_amdgcn_rcpf(1.0f + exp2f(-s1));        \
            const float r2 = __builtin_amdgcn_rcpf(1.0f + exp2f(-s2));        \
            const float r3 = __builtin_amdgcn_rcpf(1.0f + exp2f(-s3));        \
            const float gg = 2.0f * r2 - 1.0f;                                \
            c = r1 * c + r0 * gg;                                             \
            const float rt = __builtin_amdgcn_rcpf(1.0f + exp2f(-2.0f * LOG2E * c)); \
            hv = r3 * (2.0f * rt - 1.0f);                                     \
            h_lds[wv][j] = hv;   /* in-wave DS order: visible next step */    \
        }

    PREFETCH(pa0, pa1, la2);                 // step 0
    for (int t = 0; t < TT - 2; t += 2) {
        PREFETCH(pb0, pb1, lb2);             // step t+1
        STEP(pa0, pa1, la2);                 // step t
        PREFETCH(pa0, pa1, la2);             // step t+2
        STEP(pb0, pb1, lb2);                 // step t+1
    }
    PREFETCH(pb0, pb1, lb2);                 // step TT-1 (last load, in-bounds)
    STEP(pa0, pa1, la2);                     // step TT-2
    STEP(pb0, pb1, lb2);                     // step TT-1

    #undef STEP
    #undef PREFETCH

    // out[b] = dot(hT, W_lin) + b_lin -- butterfly within each 32-lane half
    float p = hv * W_lin[j];
    p += __shfl_xor(p, 1);
    p += __shfl_xor(p, 2);
    p += __shfl_xor(p, 4);
    p += __shfl_xor(p, 8);
    p += __shfl_xor(p, 16);
    if (lane == 0) out[b] = p + b_lin[0];
}

extern "C" void kernel_launch(void* const* d_in, const int* in_sizes, int n_in,
                              void* d_out, int out_size, void* d_ws, size_t ws_size,
                              hipStream_t stream) {
    const float* x     = (const float*)d_in[0];
    const float* h0    = (const float*)d_in[1];
    const float* c0    = (const float*)d_in[2];
    const float* W_ih  = (const float*)d_in[3];
    const float* W_hh  = (const float*)d_in[4];
    const float* b_ih  = (const float*)d_in[5];
    const float* b_hh  = (const float*)d_in[6];
    const float* W_lin = (const float*)d_in[7];
    const float* b_lin = (const float*)d_in[8];
    float* out = (float*)d_out;

    const int B = in_sizes[1] / HH;   // 4096
    dim3 grid(B / 4), block(256);
    lstm_fused<<<grid, block, 0, stream>>>(x, h0, c0, W_ih, W_hh, b_ih, b_hh, W_lin, b_lin, out);
}

// Round 7
// 418.142 us; speedup vs baseline: 1.4265x; 1.3719x over previous
//
#include <hip/hip_runtime.h>

#define TT 512
#define II 10
#define HH 32
#define LOG2E 1.44269504088896340736f

typedef __attribute__((ext_vector_type(8))) short bf16x8;   // 8 bf16 = 4 VGPRs (MFMA A/B frag)
typedef __attribute__((ext_vector_type(4))) float f32x4;    // MFMA C/D frag
typedef __attribute__((ext_vector_type(4))) int   i32x4;

#define MFMA(A, B, C) __builtin_amdgcn_mfma_f32_16x16x32_bf16((A), (B), (C), 0, 0, 0)
#define DPPF(v, ctrl) __builtin_bit_cast(float, __builtin_amdgcn_update_dpp(0, __builtin_bit_cast(int, (v)), (ctrl), 0xF, 0xF, true))

__device__ __forceinline__ float frcp(float v) { return __builtin_amdgcn_rcpf(v); }

__device__ __forceinline__ short bf16rne(float f) {           // round-nearest-even bf16
    unsigned u = __builtin_bit_cast(unsigned, f);
    u += 0x7fffu + ((u >> 16) & 1u);
    return (short)(u >> 16);
}
// pack {bf16(a) lo, bf16(b) hi} by truncation: single v_perm_b32
__device__ __forceinline__ unsigned pk2(float a, float b) {
    return __builtin_amdgcn_perm(__builtin_bit_cast(unsigned, b),
                                 __builtin_bit_cast(unsigned, a), 0x07060302u);
}

// MFMA LSTM: block = 16 batch rows, 4 waves; wave w owns gate-cols [32w,32w+32)
// as two 16x16 subtiles. Per step, per subtile: C = A_x*B_x + A_h*B_h where
// A = [h(k0..31) | x,bias(k32..63)] (batch rows) and B = pre-scaled weights.
// Weights live in 16 VGPRs of B-fragments -> the R1-R6 register-allocator
// fight (84 weight floats/lane never granted arch VGPRs) disappears.
// C-frag (col=lane&15,row=4*(lane>>4)+reg) is 4x4-transposed inside each lane
// quad via DPP quad_perm so each lane owns one (row,unit): activations,
// c-state (registers), h -> bf16 -> double-buffered LDS; ONE barrier/step.
// Weights pre-scaled by log2e (g-gate 2*log2e): all activations share
// rcp(1+exp2(-s)); bias rides the GEMM as virtual input k=42 (A=1.0).
extern "C" __global__ __launch_bounds__(256)
void lstm_mfma(const float* __restrict__ x,
               const float* __restrict__ h0,
               const float* __restrict__ c0,
               const float* __restrict__ W_ih,
               const float* __restrict__ W_hh,
               const float* __restrict__ b_ih,
               const float* __restrict__ b_hh,
               const float* __restrict__ W_lin,
               const float* __restrict__ b_lin,
               float* __restrict__ out)
{
    __shared__ short hbuf[2][16][40];   // bf16 h, row stride 40 (bank scramble), 16B-aligned reads
    __shared__ float plds[64];

    const int tid  = threadIdx.x;
    const int w    = tid >> 6;
    const int lane = tid & 63;
    const int n    = lane & 15;        // A: batch row m / B,C: col
    const int q    = lane >> 4;        // k-chunk / C row-group
    const int jj   = lane & 3;         // quad position (gate before transpose)
    const int R    = blockIdx.x * 16;

    // ---- B fragments (weights), built once. frag: n=lane&15, k=q*8+j ----
    bf16x8 BhA, BxA, BhB, BxB;
    for (int st = 0; st < 2; ++st) {
        const int G  = w * 32 + st * 16 + n;      // packed gatecol = unit*4+gate
        const int u  = G >> 2, g = G & 3;
        const int Wr = g * HH + u;                // row in W_ih/W_hh/biases
        const float sc = (g == 2) ? 2.0f * LOG2E : LOG2E;
        bf16x8 bh, bx;
        for (int j = 0; j < 8; ++j) {
            const int k = q * 8 + j;
            bh[j] = bf16rne(W_hh[Wr * HH + k] * sc);
            float xv = 0.0f;
            if (k < II)       xv = W_ih[Wr * II + k] * sc;
            else if (k == II) xv = (b_ih[Wr] + b_hh[Wr]) * sc;   // bias row (A has 1.0 at k=42)
            bx[j] = bf16rne(xv);
        }
        if (st == 0) { BhA = bh; BxA = bx; } else { BhB = bh; BxB = bx; }
    }
    const int uA  = 8 * w + (n >> 2);
    const int uB  = uA + 4;
    const int row = 4 * q + jj;                   // (row,unit) this lane owns post-transpose

    float cA = c0[(R + row) * HH + uA];
    float cB = c0[(R + row) * HH + uB];
    const float wlA = W_lin[uA], wlB = W_lin[uB];

    // ---- h0 -> hbuf[1] (bf16) ----
    {
        const int idx = tid * 2, r0 = idx >> 5, u0 = idx & 31;
        const float2 hv = *reinterpret_cast<const float2*>(h0 + (R + r0) * HH + u0);
        const unsigned d = ((unsigned)(unsigned short)bf16rne(hv.x)) |
                           (((unsigned)(unsigned short)bf16rne(hv.y)) << 16);
        *reinterpret_cast<unsigned*>(&hbuf[1][r0][u0]) = d;
    }

    const float* xp  = x + (size_t)(R + n) * (TT * II);
    const bool  q0b  = (q == 0), q1b = (q == 1);
    const bool  jb0  = (lane & 1), jb1 = (lane & 2);

    // pack x floats -> A-frag chunk1: q0:{x0..x7} q1:{x8,x9,1.0,0..} q2,3:0
    #define PACKA(DST, F)                                                     \
        {                                                                     \
            const unsigned p01 = pk2((F)[0], (F)[1]), p23 = pk2((F)[2], (F)[3]); \
            const unsigned p45 = pk2((F)[4], (F)[5]), p67 = pk2((F)[6], (F)[7]); \
            const unsigned p89 = pk2((F)[8], (F)[9]);                         \
            i32x4 d_;                                                         \
            d_.x = q0b ? (int)p01 : (q1b ? (int)p89 : 0);                     \
            d_.y = q0b ? (int)p23 : (q1b ? 0x00003F80 : 0);                   \
            d_.z = q0b ? (int)p45 : 0;                                        \
            d_.w = q0b ? (int)p67 : 0;                                        \
            DST = __builtin_bit_cast(bf16x8, d_);                             \
        }

    bf16x8 Ax;
    {
        float f[10];
        #pragma unroll
        for (int i = 0; i < 5; ++i) {
            const float2 t2 = *reinterpret_cast<const float2*>(xp + 2 * i);
            f[2 * i] = t2.x; f[2 * i + 1] = t2.y;
        }
        PACKA(Ax, f);
    }

    // epilogue: quad 4x4 transpose (2-stage DPP butterfly) + activations + h
    #define EPI(ACC, CST, HOUT, UU, DST)                                      \
        {                                                                     \
            float v0 = (ACC)[0], v1 = (ACC)[1], v2 = (ACC)[2], v3 = (ACC)[3]; \
            float t0 = DPPF(v1, 0xB1), t1 = DPPF(v0, 0xB1);                   \
            float t2 = DPPF(v3, 0xB1), t3 = DPPF(v2, 0xB1);                   \
            v0 = jb0 ? t0 : v0;  v1 = jb0 ? v1 : t1;                          \
            v2 = jb0 ? t2 : v2;  v3 = jb0 ? v3 : t3;                          \
            t0 = DPPF(v2, 0x4E); t1 = DPPF(v3, 0x4E);                         \
            t2 = DPPF(v0, 0x4E); t3 = DPPF(v1, 0x4E);                         \
            v0 = jb1 ? t0 : v0;  v1 = jb1 ? t1 : v1;                          \
            v2 = jb1 ? v2 : t2;  v3 = jb1 ? v3 : t3;                          \
            /* v0..v3 = pre-scaled pre-acts i,f,g,o for (row, UU) */          \
            const float r0 = frcp(1.0f + exp2f(-v0));                         \
            const float r1 = frcp(1.0f + exp2f(-v1));                         \
            const float r2 = frcp(1.0f + exp2f(-v2));                         \
            const float r3 = frcp(1.0f + exp2f(-v3));                         \
            const float gg = 2.0f * r2 - 1.0f;                                \
            CST = r1 * CST + r0 * gg;                                         \
            const float rt = frcp(1.0f + exp2f(CST * (-2.0f * LOG2E)));       \
            HOUT = r3 * (2.0f * rt - 1.0f);                                   \
            hbuf[DST][row][UU] = bf16rne(HOUT);                               \
        }

    float hA = 0.0f, hB = 0.0f;
    const f32x4 z4 = {0.0f, 0.0f, 0.0f, 0.0f};

    for (int t = 0; t < TT; ++t) {
        f32x4 accA = MFMA(Ax, BxA, z4);           // x/bias part: A ready pre-barrier
        f32x4 accB = MFMA(Ax, BxB, z4);
        __syncthreads();                           // h_{t-1} writes visible; buffers safe
        const int src = 1 - (t & 1), dst = t & 1;
        const bf16x8 Ah = *reinterpret_cast<const bf16x8*>(&hbuf[src][n][q * 8]);
        float f[10];                               // prefetch x(t+1) AFTER barrier
        {
            const int tn = (t < TT - 1) ? t + 1 : t;
            const float* px = xp + tn * II;
            #pragma unroll
            for (int i = 0; i < 5; ++i) {
                const float2 t2 = *reinterpret_cast<const float2*>(px + 2 * i);
                f[2 * i] = t2.x; f[2 * i + 1] = t2.y;
            }
        }
        accA = MFMA(Ah, BhA, accA);
        accB = MFMA(Ah, BhB, accB);
        EPI(accA, cA, hA, uA, dst);
        EPI(accB, cB, hB, uB, dst);
        PACKA(Ax, f);                              // loads have whole epilogue to land
    }
    #undef EPI
    #undef PACKA

    // out[b] = dot(hT, W_lin) + b_lin (fp32 h, pre-rounding)
    float p = hA * wlA + hB * wlB;
    p += __shfl_xor(p, 4);
    p += __shfl_xor(p, 8);
    if ((lane & 12) == 0) plds[w * 16 + row] = p;
    __syncthreads();
    if (tid < 16) {
        out[R + tid] = plds[tid] + plds[16 + tid] + plds[32 + tid] + plds[48 + tid] + b_lin[0];
    }
}

extern "C" void kernel_launch(void* const* d_in, const int* in_sizes, int n_in,
                              void* d_out, int out_size, void* d_ws, size_t ws_size,
                              hipStream_t stream) {
    const float* x     = (const float*)d_in[0];
    const float* h0    = (const float*)d_in[1];
    const float* c0    = (const float*)d_in[2];
    const float* W_ih  = (const float*)d_in[3];
    const float* W_hh  = (const float*)d_in[4];
    const float* b_ih  = (const float*)d_in[5];
    const float* b_hh  = (const float*)d_in[6];
    const float* W_lin = (const float*)d_in[7];
    const float* b_lin = (const float*)d_in[8];
    float* out = (float*)d_out;

    const int B = in_sizes[1] / HH;   // 4096
    dim3 grid(B / 16), block(256);    // 256 blocks = 1/CU, 16 rows/block
    lstm_mfma<<<grid, block, 0, stream>>>(x, h0, c0, W_ih, W_hh, b_ih, b_hh, W_lin, b_lin, out);
}

// Round 8
// 350.126 us; speedup vs baseline: 1.7036x; 1.1943x over previous
//
#include <hip/hip_runtime.h>

#define TT 512
#define II 10
#define HH 32
#define LOG2E 1.44269504088896340736f

typedef __attribute__((ext_vector_type(8))) short bf16x8;   // MFMA A/B frag (4 VGPRs)
typedef __attribute__((ext_vector_type(4))) float f32x4;    // MFMA C/D frag
typedef __attribute__((ext_vector_type(4))) int   i32x4;

#define MFMA(A, B, C) __builtin_amdgcn_mfma_f32_16x16x32_bf16((A), (B), (C), 0, 0, 0)

static __device__ __forceinline__ float frcp(float v) { return __builtin_amdgcn_rcpf(v); }
static __device__ __forceinline__ float fexp2(float v) { return __builtin_amdgcn_exp2f(v); }

static __device__ __forceinline__ short bf16rne(float f) {
    unsigned u = __builtin_bit_cast(unsigned, f);
    u += 0x7fffu + ((u >> 16) & 1u);
    return (short)(u >> 16);
}
// {bf16(a) lo, bf16(b) hi} by truncation (validated in R7): 1 v_perm_b32
static __device__ __forceinline__ unsigned pk2(float a, float b) {
    return __builtin_amdgcn_perm(__builtin_bit_cast(unsigned, b),
                                 __builtin_bit_cast(unsigned, a), 0x07060302u);
}
// same but round-to-nearest (h feeds 512 recurrent steps; avoid trunc bias)
static __device__ __forceinline__ unsigned pkh(float a, float b) {
    return __builtin_amdgcn_perm(__builtin_bit_cast(unsigned, b) + 0x8000u,
                                 __builtin_bit_cast(unsigned, a) + 0x8000u, 0x07060302u);
}

// MFMA LSTM, exchange-minimal layout. Block = 16 batch rows, 4 waves.
// A = weights (M = 128 packed gate-rows, G = unit*4+gate), B = [h | x,bias]
// (N = 16 batch). Wave w owns subtiles s in {2w, 2w+1}. C-frag gives lane
// (n=lane&15, q=lane>>4): batch n, units uA=8w+q / uB=8w+4+q, GATES IN REGS
// (no transpose). K-PERMUTATION pi(q*8+j) = 4j+q on the recurrent matmul:
// consumer lane (n,q) needs h-unit pairs (8m+q, 8m+4+q) for m=0..3 -- exactly
// what wave m's lane (n,q) produces. Exchange = 1 ds_write_b32 + 2
// ds_read2_b32 per lane per step (2-way bank alias = free), 1 barrier.
// Weights pre-scaled by log2e (g-gate 2*log2e): unified rcp(1+exp2(-s))
// activations; bias rides the x-MFMA at k=10 with B=1.0.
extern "C" __global__ __launch_bounds__(256)
__attribute__((amdgpu_waves_per_eu(1)))
void lstm_mfma(const float* __restrict__ x,
               const float* __restrict__ h0,
               const float* __restrict__ c0,
               const float* __restrict__ W_ih,
               const float* __restrict__ W_hh,
               const float* __restrict__ b_ih,
               const float* __restrict__ b_hh,
               const float* __restrict__ W_lin,
               const float* __restrict__ b_lin,
               float* __restrict__ out)
{
    __shared__ int   hx[2][4][16][4];   // [buf][producer-wave][n][q] bf16 pair
    __shared__ float plds[64];

    const int tid  = threadIdx.x;
    const int w    = tid >> 6;
    const int lane = tid & 63;
    const int n    = lane & 15;        // batch col (and A-frag row m)
    const int q    = lane >> 4;        // k-chunk / C row-group
    const int R    = blockIdx.x * 16;

    // ---- A-frags (weights), one-time. A[m=n][k=q*8+j]. ----
    // gate row in subtile s: G = 16s+n -> unit = 4s+(n>>2), gate = n&3.
    // h-part column = pi(k) = 4j+q. x-part column = k (unpermuted).
    const int   gate = n & 3;
    const float sc   = (gate == 2) ? 2.0f * LOG2E : LOG2E;
    bf16x8 AhA, AhB, AxA, AxB;
    #pragma unroll
    for (int st = 0; st < 2; ++st) {
        const int s     = 2 * w + st;
        const int unitm = 4 * s + (n >> 2);
        const int Wr    = gate * HH + unitm;
        bf16x8 ah, ax;
        #pragma unroll
        for (int j = 0; j < 8; ++j) {
            ah[j] = bf16rne(W_hh[Wr * HH + 4 * j + q] * sc);
            const int k = q * 8 + j;
            float xv = 0.0f;
            if (k < II)       xv = W_ih[Wr * II + k] * sc;
            else if (k == II) xv = (b_ih[Wr] + b_hh[Wr]) * sc;   // bias (B has 1.0 at k=10)
            ax[j] = bf16rne(xv);
        }
        if (st == 0) { AhA = ah; AxA = ax; } else { AhB = ah; AxB = ax; }
    }

    const int uA = 8 * w + q, uB = uA + 4;     // units this lane owns (batch n)
    float cA = c0[(R + n) * HH + uA];
    float cB = c0[(R + n) * HH + uB];
    const float wlA = W_lin[uA], wlB = W_lin[uB];

    // init h -> buf 0 (packed pair, exactly what consumers expect)
    hx[0][w][n][q] = (int)pkh(h0[(R + n) * HH + uA], h0[(R + n) * HH + uB]);
    __syncthreads();

    // x: every lane holds its batch row's 10 floats, prefetched 1 step ahead
    const float* xp = x + (size_t)(R + n) * (TT * II);
    float2 xl0 = *(const float2*)(xp + 0), xl1 = *(const float2*)(xp + 2),
           xl2 = *(const float2*)(xp + 4), xl3 = *(const float2*)(xp + 6),
           xl4 = *(const float2*)(xp + 8);

    const bool q0 = (q == 0), q1 = (q == 1);
    const f32x4 z4 = {0.0f, 0.0f, 0.0f, 0.0f};
    float hA = 0.0f, hB = 0.0f;

    for (int t = 0; t < TT; ++t) {
        const int rb = t & 1;
        // B_h dwords: producer-wave m = 0..3 at stride 256B (2x ds_read2_b32)
        const int b0 = hx[rb][0][n][q];
        const int b1 = hx[rb][1][n][q];
        const int b2 = hx[rb][2][n][q];
        const int b3 = hx[rb][3][n][q];

        // B_x: k=q*8+j -> q0:{x0..x7}, q1:{x8,x9,1.0,0..}, q2/q3: 0
        const unsigned d0 = q0 ? pk2(xl0.x, xl0.y) : (q1 ? pk2(xl4.x, xl4.y) : 0u);
        const unsigned d1 = q0 ? pk2(xl1.x, xl1.y) : (q1 ? 0x00003F80u : 0u);
        const unsigned d2 = q0 ? pk2(xl2.x, xl2.y) : 0u;
        const unsigned d3 = q0 ? pk2(xl3.x, xl3.y) : 0u;
        const bf16x8 Bx = __builtin_bit_cast(bf16x8, (i32x4){(int)d0, (int)d1, (int)d2, (int)d3});

        f32x4 accA = MFMA(AxA, Bx, z4);     // x part first: independent of h
        f32x4 accB = MFMA(AxB, Bx, z4);

        {   // prefetch next step's x (clamped; uniform select)
            const float* px = xp + (size_t)((t + 1 < TT) ? t + 1 : t) * II;
            xl0 = *(const float2*)(px + 0); xl1 = *(const float2*)(px + 2);
            xl2 = *(const float2*)(px + 4); xl3 = *(const float2*)(px + 6);
            xl4 = *(const float2*)(px + 8);
        }

        const bf16x8 Bh = __builtin_bit_cast(bf16x8, (i32x4){b0, b1, b2, b3});
        accA = MFMA(AhA, Bh, accA);
        accB = MFMA(AhB, Bh, accB);

        // epilogue: gates are the 4 C regs (pre-scaled) -> unified activation
        {
            const float ri = frcp(1.0f + fexp2(-accA[0]));
            const float rf = frcp(1.0f + fexp2(-accA[1]));
            const float rg = frcp(1.0f + fexp2(-accA[2]));
            const float ro = frcp(1.0f + fexp2(-accA[3]));
            cA = rf * cA + ri * (2.0f * rg - 1.0f);
            const float rt = frcp(1.0f + fexp2(cA * (-2.0f * LOG2E)));
            hA = ro * (2.0f * rt - 1.0f);
        }
        {
            const float ri = frcp(1.0f + fexp2(-accB[0]));
            const float rf = frcp(1.0f + fexp2(-accB[1]));
            const float rg = frcp(1.0f + fexp2(-accB[2]));
            const float ro = frcp(1.0f + fexp2(-accB[3]));
            cB = rf * cB + ri * (2.0f * rg - 1.0f);
            const float rt = frcp(1.0f + fexp2(cB * (-2.0f * LOG2E)));
            hB = ro * (2.0f * rt - 1.0f);
        }
        hx[1 - rb][w][n][q] = (int)pkh(hA, hB);   // next step's B_h dword
        __syncthreads();
    }

    // out[R+n] = sum_u h[n][u]*W_lin[u] + b_lin: reduce over q-groups then waves
    float p = hA * wlA + hB * wlB;
    p += __shfl_xor(p, 16);
    p += __shfl_xor(p, 32);
    if (q == 0) plds[w * 16 + n] = p;
    __syncthreads();
    if (tid < 16) {
        out[R + tid] = plds[tid] + plds[16 + tid] + plds[32 + tid] + plds[48 + tid] + b_lin[0];
    }
}

extern "C" void kernel_launch(void* const* d_in, const int* in_sizes, int n_in,
                              void* d_out, int out_size, void* d_ws, size_t ws_size,
                              hipStream_t stream) {
    const float* x     = (const float*)d_in[0];
    const float* h0    = (const float*)d_in[1];
    const float* c0    = (const float*)d_in[2];
    const float* W_ih  = (const float*)d_in[3];
    const float* W_hh  = (const float*)d_in[4];
    const float* b_ih  = (const float*)d_in[5];
    const float* b_hh  = (const float*)d_in[6];
    const float* W_lin = (const float*)d_in[7];
    const float* b_lin = (const float*)d_in[8];
    float* out = (float*)d_out;

    const int B = in_sizes[1] / HH;   // 4096
    dim3 grid(B / 16), block(256);    // 16 rows/block, 4 waves, 1 block/CU
    lstm_mfma<<<grid, block, 0, stream>>>(x, h0, c0, W_ih, W_hh, b_ih, b_hh, W_lin, b_lin, out);
}